// Round 10
// baseline (338.398 us; speedup 1.0000x reference)
//
#include <hip/hip_runtime.h>
#include <hip/hip_bf16.h>
#include <cstdint>
#include <cstddef>

// Problem constants: B=1, S=2048, H=4096, NH=32, NKV=8, D=128, GQA group=4
#define S_LEN 2048
#define HID   4096
#define NHEAD 32
#define NKVH  8
#define HD    128
#define QKV_STR 6144   // fused qkv row stride (4096 Q + 1024 K + 1024 V)

typedef __bf16 bf16x8 __attribute__((ext_vector_type(8)));
typedef float  f32x4  __attribute__((ext_vector_type(4)));
typedef float  f32x16 __attribute__((ext_vector_type(16)));
typedef unsigned uint32x2_t __attribute__((ext_vector_type(2)));

__device__ __forceinline__ unsigned short f2bf(float f) {
  union { float f; unsigned int u; } c; c.f = f;
  unsigned int u = c.u;
  return (unsigned short)((u + 0x7fffu + ((u >> 16) & 1u)) >> 16);  // RNE
}
__device__ __forceinline__ float bf2f(unsigned short b) {
  union { unsigned int u; float f; } c; c.u = ((unsigned int)b) << 16;
  return c.f;
}
__device__ __forceinline__ void gload16(const void* g, void* l) {
  __builtin_amdgcn_global_load_lds((const __attribute__((address_space(1))) void*)g,
                                   (__attribute__((address_space(3))) void*)l, 16, 0, 0);
}

// ------------------------------------------- fp32 -> bf16, 5 segments, 1 launch
__global__ void cvt_multi(const float* __restrict__ s0, const float* __restrict__ s1,
                          const float* __restrict__ s2, const float* __restrict__ s3,
                          const float* __restrict__ s4,
                          unsigned short* __restrict__ d0, unsigned short* __restrict__ d1,
                          unsigned short* __restrict__ d2, unsigned short* __restrict__ d3,
                          unsigned short* __restrict__ d4,
                          int n0, int n1, int n2, int n3, int n4c) {
  const float* src; unsigned short* dst; int n;
  switch (blockIdx.y) {
    case 0: src = s0; dst = d0; n = n0; break;
    case 1: src = s1; dst = d1; n = n1; break;
    case 2: src = s2; dst = d2; n = n2; break;
    case 3: src = s3; dst = d3; n = n3; break;
    default: src = s4; dst = d4; n = n4c; break;
  }
  int i = blockIdx.x * blockDim.x + threadIdx.x;
  int stride = gridDim.x * blockDim.x;
  for (; i < n; i += stride) {
    float4 v = ((const float4*)src)[i];
    ushort4 o;
    o.x = f2bf(v.x); o.y = f2bf(v.y); o.z = f2bf(v.z); o.w = f2bf(v.w);
    ((ushort4*)dst)[i] = o;
  }
}

// ------------------------------------------------- C[M,N] = A[M,K] * B[N,K]^T
// R5-proven structure: 128x128 tile, BK=32, 4 waves, triple-buffered LDS with
// counted vmcnt across the barrier (T3/T4); chunk swizzle (row>>1)&3 via
// pre-swizzled global source (rule #21).  Measured: 126 us QKV, MfmaUtil 35%,
// SQ_LDS_BANK_CONFLICT 0, ~3 blocks/CU.  M hard-coded 2048 (16 block-rows).
template <bool F32OUT>
__global__ __launch_bounds__(256)
void gemm_bt(const unsigned short* __restrict__ A,
             const unsigned short* __restrict__ Bm,
             void* __restrict__ Cout, int N, int K) {
  __shared__ __align__(16) unsigned short lA[3][128 * 32];
  __shared__ __align__(16) unsigned short lB[3][128 * 32];
  const int tid = threadIdx.x;
  const int lane = tid & 63, wid = tid >> 6;
  const int l15 = lane & 15, lg = lane >> 4;
  const int wr = (wid >> 1) * 64, wc = (wid & 1) * 64;
  // XCD swizzle (nwg % 8 == 0 for both call sites), bm-fastest
  const int nwg = gridDim.x * 16;
  int bid = blockIdx.x + blockIdx.y * gridDim.x;
  bid = (bid & 7) * (nwg >> 3) + (bid >> 3);
  const int bm = bid & 15, bn = bid >> 4;

  f32x4 acc[4][4] = {};
  const unsigned short* Ab = A + (size_t)bm * 128 * K;
  const unsigned short* Bb = Bm + (size_t)bn * 128 * K;

  auto stage = [&](int t, int buf) {
    const int k0 = t * 32;
#pragma unroll
    for (int i = 0; i < 2; ++i) {     // 4 gloads/thread per tile (2 A + 2 B)
      int c = tid + i * 256;
      int row = c >> 2, sl = c & 3;
      int g = sl ^ ((row >> 1) & 3);  // inverse chunk swizzle on source
      gload16(Ab + (size_t)row * K + k0 + g * 8, (char*)lA[buf] + c * 16);
      gload16(Bb + (size_t)row * K + k0 + g * 8, (char*)lB[buf] + c * 16);
    }
  };

  const int nt = K / 32;
  stage(0, 0);
  if (nt > 1) stage(1, 1);
  const int swz = (l15 >> 1) & 3;     // read-side chunk swizzle (lane-constant)

  int cur = 0;
  for (int t = 0; t < nt; ++t) {
    if (t + 1 < nt) asm volatile("s_waitcnt vmcnt(4)" ::: "memory");
    else            asm volatile("s_waitcnt vmcnt(0)" ::: "memory");
    __builtin_amdgcn_s_barrier();
    __builtin_amdgcn_sched_barrier(0);
    if (t + 2 < nt) { int nb = cur + 2; if (nb >= 3) nb -= 3; stage(t + 2, nb); }
    bf16x8 af[4], bfr[4];
#pragma unroll
    for (int m = 0; m < 4; ++m)
      af[m] = *(const bf16x8*)&lA[cur][(wr + m * 16 + l15) * 32 + ((lg ^ swz) * 8)];
#pragma unroll
    for (int n = 0; n < 4; ++n)
      bfr[n] = *(const bf16x8*)&lB[cur][(wc + n * 16 + l15) * 32 + ((lg ^ swz) * 8)];
#pragma unroll
    for (int m = 0; m < 4; ++m)
#pragma unroll
      for (int n = 0; n < 4; ++n)
        acc[m][n] = __builtin_amdgcn_mfma_f32_16x16x32_bf16(af[m], bfr[n], acc[m][n], 0, 0, 0);
    ++cur; if (cur >= 3) cur -= 3;
  }
  // epilogue: C layout col=lane&15, row=4*(lane>>4)+reg
  const int r0 = bm * 128 + wr + 4 * lg;
  const int c0 = bn * 128 + wc + l15;
#pragma unroll
  for (int m = 0; m < 4; ++m)
#pragma unroll
    for (int n = 0; n < 4; ++n)
#pragma unroll
      for (int j = 0; j < 4; ++j) {
        size_t idx = (size_t)(r0 + m * 16 + j) * N + (c0 + n * 16);
        if (F32OUT) ((float*)Cout)[idx] = acc[m][n][j];
        else        ((unsigned short*)Cout)[idx] = f2bf(acc[m][n][j]);
      }
}

// -------------------- K-RoPE (in place) + V transpose, one launch
// grid (16, 8): block handles rows [s0, s0+128) of kv head kvh.
// Part 1: rope on K cols (disjoint from V).  Part 2: V tile transpose into
// VT[kvh][d][s] via XOR-swizzled LDS (chunk ^= (s^(s>>3))&7).
__global__ __launch_bounds__(256)
void rope_transpose(unsigned short* __restrict__ qkv,
                    const float* __restrict__ cp,
                    const float* __restrict__ sp,
                    unsigned short* __restrict__ VT) {
  __shared__ __align__(16) unsigned short tile[128 * 128];
  const int tid = threadIdx.x;
  const int s0 = blockIdx.x * 128;
  const int kvh = blockIdx.y;
  // --- K-RoPE: 128 rows x 64 pairs = 8192 pairs, 32 per thread
  unsigned short* K = qkv + 4096 + kvh * 128;
#pragma unroll 4
  for (int i = 0; i < 32; ++i) {
    int idx = tid + i * 256;
    int sl = idx >> 6, d = idx & 63;
    float c = cp[(size_t)(s0 + sl) * 128 + d];
    float sn = sp[(size_t)(s0 + sl) * 128 + d];
    size_t base = (size_t)(s0 + sl) * QKV_STR + d;
    float x1 = bf2f(K[base]), x2 = bf2f(K[base + 64]);
    K[base]      = f2bf(x1 * c - x2 * sn);
    K[base + 64] = f2bf(x2 * c + x1 * sn);
  }
  // --- V transpose
  const unsigned short* src = qkv + 5120 + kvh * 128;
#pragma unroll
  for (int i = 0; i < 8; ++i) {
    int c = tid + i * 256;
    int s = c >> 4, dc = c & 15;
    int f = (s ^ (s >> 3)) & 7;
    uint4 v = *(const uint4*)(src + (size_t)(s0 + s) * QKV_STR + dc * 8);
    *(uint4*)&tile[s * 128 + ((dc ^ f) * 8)] = v;
  }
  __syncthreads();
#pragma unroll
  for (int i = 0; i < 8; ++i) {
    int c = tid + i * 256;
    int d = c >> 4, sc = c & 15;
    unsigned short tmp[8];
#pragma unroll
    for (int j = 0; j < 8; ++j) {
      int s = sc * 8 + j;
      int f = (s ^ (s >> 3)) & 7;
      tmp[j] = tile[s * 128 + (((d >> 3) ^ f) * 8) + (d & 7)];
    }
    *(uint4*)(VT + ((size_t)kvh * 128 + d) * S_LEN + s0 + sc * 8) = *(uint4*)tmp;
  }
}

// ------------------------------------------------------------ flash attention
// Swapped-QK^T 32x32: grid (16 qtiles, 32 heads), 4 waves x 32 q-rows.
// st = mfma(K,Q): lane owns q = lane&31 (col); rows = kv.
// accO^T = mfma(V^T, P): rows = d, cols = q  ->  corr / 1/l are LANE-LOCAL.
// K and V^T both staged via source-swizzled global_load_lds (no ds_writes).
// Q-RoPE fused in the prologue.  MERGED 64-kv softmax: one max/shfl/vote/
// corr/sum chain per tile (was 2) — halves serial fixed-latency cost.
// P->B-frag pack via permlane32_swap (T12); defer-max threshold 8 (T13).
// LOAD BALANCE: 512 blocks co-resident (2/CU); CU c holds blocks c, c+256
// (same bx).  Anti-paired qt across grid halves -> each CU pair sums to 15.
#define CROW(r) (((r) & 3) + 8 * ((r) >> 2) + 4 * hi)
#define MAX3(a, b, c) fmaxf(fmaxf(a, b), c)
__global__ __launch_bounds__(256, 2)
void flash_attn(const unsigned short* __restrict__ qkv,
                const unsigned short* __restrict__ VT,
                const float* __restrict__ cp,
                const float* __restrict__ sp,
                unsigned short* __restrict__ Og) {
  __shared__ __align__(16) unsigned short lK[2 * 64 * 128];
  __shared__ __align__(16) unsigned short lVt[2 * 128 * 64];
  const int tid = threadIdx.x;
  const int lane = tid & 63, w = tid >> 6;
  const int l31 = lane & 31, hi = lane >> 5;
  const int h = blockIdx.y, kvh = h >> 2;
  const int qt = (h & 16) ? blockIdx.x : (15 - blockIdx.x);  // anti-paired halves
  const int nt = 2 * qt + 2;
  const int qminw = qt * 128 + w * 32;
  const int qlane = qminw + l31;
  const int qmaxw = qminw + 31;
  const float S2 = 0.12752960f;                      // (1/sqrt(128))*log2(e)

  bf16x8 qf[8];
  {
    const unsigned short* qp = qkv + (size_t)qlane * QKV_STR + h * HD + hi * 8;
#pragma unroll
    for (int ks = 0; ks < 8; ++ks) qf[ks] = *(const bf16x8*)(qp + ks * 16);
    // fused Q-RoPE: d = ks*16 + hi*8 + j (ks<4 -> d<64), pair at qf[ks+4]
    const float* crow = cp + (size_t)qlane * 128 + hi * 8;
    const float* srow = sp + (size_t)qlane * 128 + hi * 8;
#pragma unroll
    for (int ks = 0; ks < 4; ++ks) {
      float4 c0 = *(const float4*)(crow + ks * 16);
      float4 c1 = *(const float4*)(crow + ks * 16 + 4);
      float4 s0 = *(const float4*)(srow + ks * 16);
      float4 s1 = *(const float4*)(srow + ks * 16 + 4);
      float cc[8] = {c0.x, c0.y, c0.z, c0.w, c1.x, c1.y, c1.z, c1.w};
      float ss[8] = {s0.x, s0.y, s0.z, s0.w, s1.x, s1.y, s1.z, s1.w};
#pragma unroll
      for (int j = 0; j < 8; ++j) {
        float x1 = (float)qf[ks][j], x2 = (float)qf[ks + 4][j];
        qf[ks][j]     = (__bf16)(x1 * cc[j] - x2 * ss[j]);
        qf[ks + 4][j] = (__bf16)(x2 * cc[j] + x1 * ss[j]);
      }
    }
  }
  f32x16 accO[4] = {};
  float m_run = -3e38f, l_run = 0.f;

  const unsigned short* Kb0 = qkv + 4096 + kvh * HD;
  const unsigned short* VTh = VT + (size_t)kvh * 128 * S_LEN;

  auto stageK = [&](int t, int buf) {
    const unsigned short* Kb = Kb0 + (size_t)(t * 64) * QKV_STR;
    char* dst = (char*)(lK + buf * (64 * 128));
#pragma unroll
    for (int i = 0; i < 4; ++i) {
      int c = tid + i * 256;
      int row = c >> 4, s = c & 15;
      gload16(Kb + (size_t)row * QKV_STR + ((s ^ (row & 7)) * 8), dst + c * 16);
    }
  };
  auto stageV = [&](int t, int buf) {
    const unsigned short* Vb = VTh + t * 64;
    char* dst = (char*)(lVt + buf * (128 * 64));
#pragma unroll
    for (int i = 0; i < 4; ++i) {
      int c = tid + i * 256;
      int d = c >> 3, s = c & 7;
      gload16(Vb + (size_t)d * S_LEN + ((s ^ (d & 7)) * 8), dst + c * 16);
    }
  };

  stageK(0, 0);
  stageV(0, 0);
  __syncthreads();

  int cur = 0;
  for (int t = 0; t < nt; ++t) {
    const bool pf = (t + 1 < nt);
    if (pf) { stageK(t + 1, cur ^ 1); stageV(t + 1, cur ^ 1); }

    const int kvb0 = t * 64, kvb1 = kvb0 + 32;
    if (kvb0 <= qmaxw) {                             // wave-uniform
      const bool live1 = (kvb1 <= qmaxw);            // wave-uniform
      const unsigned short* lKc = lK + cur * (64 * 128);
      f32x16 st0 = {}, st1 = {};
      __builtin_amdgcn_s_setprio(1);
#pragma unroll
      for (int ks = 0; ks < 8; ++ks) {
        bf16x8 kf = *(const bf16x8*)&lKc[l31 * 128 + (((ks * 2 + hi) ^ (l31 & 7)) * 8)];
        st0 = __builtin_amdgcn_mfma_f32_32x32x16_bf16(kf, qf[ks], st0, 0, 0, 0);
      }
      if (live1) {
        const unsigned short* lKc1 = lKc + 32 * 128;
#pragma unroll
        for (int ks = 0; ks < 8; ++ks) {
          bf16x8 kf = *(const bf16x8*)&lKc1[l31 * 128 + (((ks * 2 + hi) ^ (l31 & 7)) * 8)];
          st1 = __builtin_amdgcn_mfma_f32_32x32x16_bf16(kf, qf[ks], st1, 0, 0, 0);
        }
      }
      __builtin_amdgcn_s_setprio(0);
      // causal masks
      if (kvb0 + 31 > qminw) {
#pragma unroll
        for (int r = 0; r < 16; ++r)
          if (kvb0 + CROW(r) > qlane) st0[r] = -3e38f;
      }
      if (live1) {
        if (kvb1 + 31 > qminw) {
#pragma unroll
          for (int r = 0; r < 16; ++r)
            if (kvb1 + CROW(r) > qlane) st1[r] = -3e38f;
        }
      } else {
#pragma unroll
        for (int r = 0; r < 16; ++r) st1[r] = -3e38f;
      }
      // single merged softmax over 32 regs (max3-fusable triples)
      float u0 = MAX3(st0[0], st0[1], st0[2]);
      float u1 = MAX3(st0[3], st0[4], st0[5]);
      float u2 = MAX3(st0[6], st0[7], st0[8]);
      float u3 = MAX3(st0[9], st0[10], st0[11]);
      float u4 = MAX3(st0[12], st0[13], st0[14]);
      float u5 = MAX3(st0[15], st1[0], st1[1]);
      float u6 = MAX3(st1[2], st1[3], st1[4]);
      float u7 = MAX3(st1[5], st1[6], st1[7]);
      float u8 = MAX3(st1[8], st1[9], st1[10]);
      float u9 = MAX3(st1[11], st1[12], st1[13]);
      float uA = fmaxf(st1[14], st1[15]);
      float v0 = MAX3(u0, u1, u2);
      float v1 = MAX3(u3, u4, u5);
      float v2 = MAX3(u6, u7, u8);
      float v3 = fmaxf(u9, uA);
      float tm = fmaxf(fmaxf(v0, v1), fmaxf(v2, v3));
      tm = fmaxf(tm, __shfl_xor(tm, 32));
      // defer-max (T13): skip rescale while p stays bounded by 2^8
      const bool skip = __all((tm - m_run) * S2 <= 8.0f);
      float corr = 1.f;
      if (!skip) {
        float mnew = fmaxf(m_run, tm);
        corr = __builtin_amdgcn_exp2f((m_run - mnew) * S2);
        m_run = mnew;
      }
      const float mS2 = m_run * S2;
#pragma unroll
      for (int r = 0; r < 16; ++r) st0[r] = __builtin_amdgcn_exp2f(st0[r] * S2 - mS2);
#pragma unroll
      for (int r = 0; r < 16; ++r) st1[r] = __builtin_amdgcn_exp2f(st1[r] * S2 - mS2);
      float a0 = (st0[0] + st0[1]) + (st0[2] + st0[3]);
      float a1 = (st0[4] + st0[5]) + (st0[6] + st0[7]);
      float a2 = (st0[8] + st0[9]) + (st0[10] + st0[11]);
      float a3 = (st0[12] + st0[13]) + (st0[14] + st0[15]);
      float a4 = (st1[0] + st1[1]) + (st1[2] + st1[3]);
      float a5 = (st1[4] + st1[5]) + (st1[6] + st1[7]);
      float a6 = (st1[8] + st1[9]) + (st1[10] + st1[11]);
      float a7 = (st1[12] + st1[13]) + (st1[14] + st1[15]);
      float rsum = ((a0 + a1) + (a2 + a3)) + ((a4 + a5) + (a6 + a7));
      rsum += __shfl_xor(rsum, 32);
      l_run = l_run * corr + rsum;
      if (!skip) {
#pragma unroll
        for (int db = 0; db < 4; ++db) accO[db] = accO[db] * corr;   // lane-local
      }
      // pack P -> B-fragments (in-register, T12 permlane32_swap)
      bf16x8 pa00, pa01, pa10 = {}, pa11 = {};
      {
        unsigned wpk[8];
#pragma unroll
        for (int i = 0; i < 8; ++i) {
          __hip_bfloat162 b2 = __float22bfloat162_rn(float2{st0[2 * i], st0[2 * i + 1]});
          wpk[i] = *(unsigned*)&b2;
        }
        int4 p0i, p1i;
#if __has_builtin(__builtin_amdgcn_permlane32_swap)
        uint32x2_t r0 = __builtin_amdgcn_permlane32_swap(wpk[0], wpk[2], false, false);
        uint32x2_t r1 = __builtin_amdgcn_permlane32_swap(wpk[1], wpk[3], false, false);
        uint32x2_t r2 = __builtin_amdgcn_permlane32_swap(wpk[4], wpk[6], false, false);
        uint32x2_t r3 = __builtin_amdgcn_permlane32_swap(wpk[5], wpk[7], false, false);
        p0i.x = (int)r0.x; p0i.y = (int)r1.x; p0i.z = (int)r0.y; p0i.w = (int)r1.y;
        p1i.x = (int)r2.x; p1i.y = (int)r3.x; p1i.z = (int)r2.y; p1i.w = (int)r3.y;
#else
        unsigned xpk[8];
#pragma unroll
        for (int i = 0; i < 8; ++i) xpk[i] = (unsigned)__shfl_xor((int)wpk[i], 32);
        p0i.x = hi ? (int)xpk[2] : (int)wpk[0]; p0i.y = hi ? (int)xpk[3] : (int)wpk[1];
        p0i.z = hi ? (int)wpk[2] : (int)xpk[0]; p0i.w = hi ? (int)wpk[3] : (int)xpk[1];
        p1i.x = hi ? (int)xpk[6] : (int)wpk[4]; p1i.y = hi ? (int)xpk[7] : (int)wpk[5];
        p1i.z = hi ? (int)wpk[6] : (int)xpk[4]; p1i.w = hi ? (int)wpk[7] : (int)xpk[5];
#endif
        pa00 = *(bf16x8*)&p0i; pa01 = *(bf16x8*)&p1i;
      }
      if (live1) {
        unsigned wpk[8];
#pragma unroll
        for (int i = 0; i < 8; ++i) {
          __hip_bfloat162 b2 = __float22bfloat162_rn(float2{st1[2 * i], st1[2 * i + 1]});
          wpk[i] = *(unsigned*)&b2;
        }
        int4 p0i, p1i;
#if __has_builtin(__builtin_amdgcn_permlane32_swap)
        uint32x2_t r0 = __builtin_amdgcn_permlane32_swap(wpk[0], wpk[2], false, false);
        uint32x2_t r1 = __builtin_amdgcn_permlane32_swap(wpk[1], wpk[3], false, false);
        uint32x2_t r2 = __builtin_amdgcn_permlane32_swap(wpk[4], wpk[6], false, false);
        uint32x2_t r3 = __builtin_amdgcn_permlane32_swap(wpk[5], wpk[7], false, false);
        p0i.x = (int)r0.x; p0i.y = (int)r1.x; p0i.z = (int)r0.y; p0i.w = (int)r1.y;
        p1i.x = (int)r2.x; p1i.y = (int)r3.x; p1i.z = (int)r2.y; p1i.w = (int)r3.y;
#else
        unsigned xpk[8];
#pragma unroll
        for (int i = 0; i < 8; ++i) xpk[i] = (unsigned)__shfl_xor((int)wpk[i], 32);
        p0i.x = hi ? (int)xpk[2] : (int)wpk[0]; p0i.y = hi ? (int)xpk[3] : (int)wpk[1];
        p0i.z = hi ? (int)wpk[2] : (int)xpk[0]; p0i.w = hi ? (int)wpk[3] : (int)xpk[1];
        p1i.x = hi ? (int)xpk[6] : (int)wpk[4]; p1i.y = hi ? (int)xpk[7] : (int)wpk[5];
        p1i.z = hi ? (int)wpk[6] : (int)xpk[4]; p1i.w = hi ? (int)wpk[7] : (int)xpk[5];
#endif
        pa10 = *(bf16x8*)&p0i; pa11 = *(bf16x8*)&p1i;
      }
      // PV: accO^T[d][q] += V^T[d][kv] * P[kv][q]  (both chunks, one burst)
      const unsigned short* lVc = lVt + cur * (128 * 64);
      __builtin_amdgcn_s_setprio(1);
#pragma unroll
      for (int db = 0; db < 4; ++db) {
        int d = db * 32 + l31;
        int dsw = d & 7;
        bf16x8 vf;
        vf = *(const bf16x8*)&lVc[d * 64 + (((0 + hi) ^ dsw) * 8)];
        accO[db] = __builtin_amdgcn_mfma_f32_32x32x16_bf16(vf, pa00, accO[db], 0, 0, 0);
        vf = *(const bf16x8*)&lVc[d * 64 + (((2 + hi) ^ dsw) * 8)];
        accO[db] = __builtin_amdgcn_mfma_f32_32x32x16_bf16(vf, pa01, accO[db], 0, 0, 0);
        if (live1) {
          vf = *(const bf16x8*)&lVc[d * 64 + (((4 + hi) ^ dsw) * 8)];
          accO[db] = __builtin_amdgcn_mfma_f32_32x32x16_bf16(vf, pa10, accO[db], 0, 0, 0);
          vf = *(const bf16x8*)&lVc[d * 64 + (((6 + hi) ^ dsw) * 8)];
          accO[db] = __builtin_amdgcn_mfma_f32_32x32x16_bf16(vf, pa11, accO[db], 0, 0, 0);
        }
      }
      __builtin_amdgcn_s_setprio(0);
    }
    __syncthreads();   // drains vmcnt: next tile fully staged
    cur ^= 1;
  }

  // epilogue: lane owns column q; invl lane-local; packed 8B stores
  const float invl = 1.0f / l_run;
  unsigned short* orow = Og + (size_t)(qt * 128 + w * 32 + l31) * HID + h * HD;
#pragma unroll
  for (int db = 0; db < 4; ++db)
#pragma unroll
    for (int rr = 0; rr < 4; ++rr) {
      int d0 = db * 32 + rr * 8 + 4 * hi;
      ushort4 o;
      o.x = f2bf(accO[db][rr * 4 + 0] * invl);
      o.y = f2bf(accO[db][rr * 4 + 1] * invl);
      o.z = f2bf(accO[db][rr * 4 + 2] * invl);
      o.w = f2bf(accO[db][rr * 4 + 3] * invl);
      *(ushort4*)(orow + d0) = o;
    }
}

// ---------------------------------------------------------------------- launch
extern "C" void kernel_launch(void* const* d_in, const int* in_sizes, int n_in,
                              void* d_out, int out_size, void* d_ws, size_t ws_size,
                              hipStream_t stream) {
  const float* hs   = (const float*)d_in[0];
  const float* cosp = (const float*)d_in[1];
  const float* sinp = (const float*)d_in[2];
  const float* Wq = (const float*)d_in[4];
  const float* Wk = (const float*)d_in[5];
  const float* Wv = (const float*)d_in[6];
  const float* Wo = (const float*)d_in[7];
  float* out = (float*)d_out;

  uint8_t* ws = (uint8_t*)d_ws;
  size_t off = 0;
  auto alloc = [&](size_t bytes) { void* p = ws + off; off += bytes; return p; };
  unsigned short* hidB  = (unsigned short*)alloc((size_t)S_LEN * HID * 2);
  unsigned short* wqkvB = (unsigned short*)alloc((size_t)QKV_STR * HID * 2);
  unsigned short* woB   = (unsigned short*)alloc((size_t)HID * HID * 2);
  unsigned short* qkvB  = (unsigned short*)alloc((size_t)S_LEN * QKV_STR * 2);
  unsigned short* aoB   = (unsigned short*)alloc((size_t)S_LEN * HID * 2);
  unsigned short* vtB   = (unsigned short*)alloc((size_t)NKVH * HD * S_LEN * 2);

  // 1. fp32 -> bf16, all five tensors in one launch
  cvt_multi<<<dim3(1024, 5), 256, 0, stream>>>(
      hs, Wq, Wk, Wv, Wo,
      hidB, wqkvB, wqkvB + (size_t)HID * HID, wqkvB + (size_t)(HID + 1024) * HID, woB,
      S_LEN * HID / 4, HID * HID / 4, 1024 * HID / 4, 1024 * HID / 4, HID * HID / 4);

  // 2. fused QKV projection: [2048][6144] = hid @ WqkvT  (R5-proven 128x128)
  gemm_bt<false><<<dim3(QKV_STR / 128, S_LEN / 128), 256, 0, stream>>>(
      hidB, wqkvB, qkvB, QKV_STR, HID);

  // 3. K-RoPE (in place) + V transpose, one launch
  rope_transpose<<<dim3(S_LEN / 128, NKVH), 256, 0, stream>>>(qkvB, cosp, sinp, vtB);

  // 4. flash attention (swapped 32x32, fused Q-RoPE, merged 64-kv softmax)
  flash_attn<<<dim3(S_LEN / 128, NHEAD), 256, 0, stream>>>(qkvB, vtB, cosp, sinp, aoB);

  // 5. output projection, fp32 straight to d_out (R5-proven 128x128)
  gemm_bt<true><<<dim3(HID / 128, S_LEN / 128), 256, 0, stream>>>(
      aoB, woB, out, HID, HID);
}

// Round 11
// 335.730 us; speedup vs baseline: 1.0079x; 1.0079x over previous
//
#include <hip/hip_runtime.h>
#include <hip/hip_bf16.h>
#include <cstdint>
#include <cstddef>

// Problem constants: B=1, S=2048, H=4096, NH=32, NKV=8, D=128, GQA group=4
#define S_LEN 2048
#define HID   4096
#define NHEAD 32
#define NKVH  8
#define HD    128
#define QKV_STR 6144   // fused qkv row stride (4096 Q + 1024 K + 1024 V)

typedef __bf16 bf16x8 __attribute__((ext_vector_type(8)));
typedef float  f32x4  __attribute__((ext_vector_type(4)));
typedef float  f32x16 __attribute__((ext_vector_type(16)));
typedef unsigned uint32x2_t __attribute__((ext_vector_type(2)));

__device__ __forceinline__ unsigned short f2bf(float f) {
  union { float f; unsigned int u; } c; c.f = f;
  unsigned int u = c.u;
  return (unsigned short)((u + 0x7fffu + ((u >> 16) & 1u)) >> 16);  // RNE
}
__device__ __forceinline__ float bf2f(unsigned short b) {
  union { unsigned int u; float f; } c; c.u = ((unsigned int)b) << 16;
  return c.f;
}
__device__ __forceinline__ void gload16(const void* g, void* l) {
  __builtin_amdgcn_global_load_lds((const __attribute__((address_space(1))) void*)g,
                                   (__attribute__((address_space(3))) void*)l, 16, 0, 0);
}

// ------------------------------------------- fp32 -> bf16, 4 segments, 1 launch
// (Wo conversion is folded into flash_attn's epilogue slack)
__global__ void cvt_multi(const float* __restrict__ s0, const float* __restrict__ s1,
                          const float* __restrict__ s2, const float* __restrict__ s3,
                          unsigned short* __restrict__ d0, unsigned short* __restrict__ d1,
                          unsigned short* __restrict__ d2, unsigned short* __restrict__ d3,
                          int n0, int n1, int n2, int n3) {
  const float* src; unsigned short* dst; int n;
  switch (blockIdx.y) {
    case 0: src = s0; dst = d0; n = n0; break;
    case 1: src = s1; dst = d1; n = n1; break;
    case 2: src = s2; dst = d2; n = n2; break;
    default: src = s3; dst = d3; n = n3; break;
  }
  int i = blockIdx.x * blockDim.x + threadIdx.x;
  int stride = gridDim.x * blockDim.x;
  for (; i < n; i += stride) {
    float4 v = ((const float4*)src)[i];
    ushort4 o;
    o.x = f2bf(v.x); o.y = f2bf(v.y); o.z = f2bf(v.z); o.w = f2bf(v.w);
    ((ushort4*)dst)[i] = o;
  }
}

// ------------------------------------------------- C[M,N] = A[M,K] * B[N,K]^T
// R5-proven structure: 128x128 tile, BK=32, 4 waves, triple-buffered LDS with
// counted vmcnt across the barrier (T3/T4); chunk swizzle (row>>1)&3 via
// pre-swizzled global source (rule #21).  Measured: ~122 us QKV, MfmaUtil 36%,
// SQ_LDS_BANK_CONFLICT 0, ~3 blocks/CU.  M hard-coded 2048 (16 block-rows).
template <bool F32OUT>
__global__ __launch_bounds__(256)
void gemm_bt(const unsigned short* __restrict__ A,
             const unsigned short* __restrict__ Bm,
             void* __restrict__ Cout, int N, int K) {
  __shared__ __align__(16) unsigned short lA[3][128 * 32];
  __shared__ __align__(16) unsigned short lB[3][128 * 32];
  const int tid = threadIdx.x;
  const int lane = tid & 63, wid = tid >> 6;
  const int l15 = lane & 15, lg = lane >> 4;
  const int wr = (wid >> 1) * 64, wc = (wid & 1) * 64;
  // XCD swizzle (nwg % 8 == 0 for both call sites), bm-fastest
  const int nwg = gridDim.x * 16;
  int bid = blockIdx.x + blockIdx.y * gridDim.x;
  bid = (bid & 7) * (nwg >> 3) + (bid >> 3);
  const int bm = bid & 15, bn = bid >> 4;

  f32x4 acc[4][4] = {};
  const unsigned short* Ab = A + (size_t)bm * 128 * K;
  const unsigned short* Bb = Bm + (size_t)bn * 128 * K;

  auto stage = [&](int t, int buf) {
    const int k0 = t * 32;
#pragma unroll
    for (int i = 0; i < 2; ++i) {     // 4 gloads/thread per tile (2 A + 2 B)
      int c = tid + i * 256;
      int row = c >> 2, sl = c & 3;
      int g = sl ^ ((row >> 1) & 3);  // inverse chunk swizzle on source
      gload16(Ab + (size_t)row * K + k0 + g * 8, (char*)lA[buf] + c * 16);
      gload16(Bb + (size_t)row * K + k0 + g * 8, (char*)lB[buf] + c * 16);
    }
  };

  const int nt = K / 32;
  stage(0, 0);
  if (nt > 1) stage(1, 1);
  const int swz = (l15 >> 1) & 3;     // read-side chunk swizzle (lane-constant)

  int cur = 0;
  for (int t = 0; t < nt; ++t) {
    if (t + 1 < nt) asm volatile("s_waitcnt vmcnt(4)" ::: "memory");
    else            asm volatile("s_waitcnt vmcnt(0)" ::: "memory");
    __builtin_amdgcn_s_barrier();
    __builtin_amdgcn_sched_barrier(0);
    if (t + 2 < nt) { int nb = cur + 2; if (nb >= 3) nb -= 3; stage(t + 2, nb); }
    bf16x8 af[4], bfr[4];
#pragma unroll
    for (int m = 0; m < 4; ++m)
      af[m] = *(const bf16x8*)&lA[cur][(wr + m * 16 + l15) * 32 + ((lg ^ swz) * 8)];
#pragma unroll
    for (int n = 0; n < 4; ++n)
      bfr[n] = *(const bf16x8*)&lB[cur][(wc + n * 16 + l15) * 32 + ((lg ^ swz) * 8)];
#pragma unroll
    for (int m = 0; m < 4; ++m)
#pragma unroll
      for (int n = 0; n < 4; ++n)
        acc[m][n] = __builtin_amdgcn_mfma_f32_16x16x32_bf16(af[m], bfr[n], acc[m][n], 0, 0, 0);
    ++cur; if (cur >= 3) cur -= 3;
  }
  // epilogue: C layout col=lane&15, row=4*(lane>>4)+reg
  const int r0 = bm * 128 + wr + 4 * lg;
  const int c0 = bn * 128 + wc + l15;
#pragma unroll
  for (int m = 0; m < 4; ++m)
#pragma unroll
    for (int n = 0; n < 4; ++n)
#pragma unroll
      for (int j = 0; j < 4; ++j) {
        size_t idx = (size_t)(r0 + m * 16 + j) * N + (c0 + n * 16);
        if (F32OUT) ((float*)Cout)[idx] = acc[m][n][j];
        else        ((unsigned short*)Cout)[idx] = f2bf(acc[m][n][j]);
      }
}

// -------------------- K-RoPE (in place) + V transpose, one launch
// grid (16, 8): block handles rows [s0, s0+128) of kv head kvh.
__global__ __launch_bounds__(256)
void rope_transpose(unsigned short* __restrict__ qkv,
                    const float* __restrict__ cp,
                    const float* __restrict__ sp,
                    unsigned short* __restrict__ VT) {
  __shared__ __align__(16) unsigned short tile[128 * 128];
  const int tid = threadIdx.x;
  const int s0 = blockIdx.x * 128;
  const int kvh = blockIdx.y;
  // --- K-RoPE: 128 rows x 64 pairs = 8192 pairs, 32 per thread
  unsigned short* K = qkv + 4096 + kvh * 128;
#pragma unroll 4
  for (int i = 0; i < 32; ++i) {
    int idx = tid + i * 256;
    int sl = idx >> 6, d = idx & 63;
    float c = cp[(size_t)(s0 + sl) * 128 + d];
    float sn = sp[(size_t)(s0 + sl) * 128 + d];
    size_t base = (size_t)(s0 + sl) * QKV_STR + d;
    float x1 = bf2f(K[base]), x2 = bf2f(K[base + 64]);
    K[base]      = f2bf(x1 * c - x2 * sn);
    K[base + 64] = f2bf(x2 * c + x1 * sn);
  }
  // --- V transpose
  const unsigned short* src = qkv + 5120 + kvh * 128;
#pragma unroll
  for (int i = 0; i < 8; ++i) {
    int c = tid + i * 256;
    int s = c >> 4, dc = c & 15;
    int f = (s ^ (s >> 3)) & 7;
    uint4 v = *(const uint4*)(src + (size_t)(s0 + s) * QKV_STR + dc * 8);
    *(uint4*)&tile[s * 128 + ((dc ^ f) * 8)] = v;
  }
  __syncthreads();
#pragma unroll
  for (int i = 0; i < 8; ++i) {
    int c = tid + i * 256;
    int d = c >> 4, sc = c & 15;
    unsigned short tmp[8];
#pragma unroll
    for (int j = 0; j < 8; ++j) {
      int s = sc * 8 + j;
      int f = (s ^ (s >> 3)) & 7;
      tmp[j] = tile[s * 128 + (((d >> 3) ^ f) * 8) + (d & 7)];
    }
    *(uint4*)(VT + ((size_t)kvh * 128 + d) * S_LEN + s0 + sc * 8) = *(uint4*)tmp;
  }
}

// ------------------------------------------------------------ flash attention
// Swapped-QK^T 32x32 (R9-proven loop): grid (16 qtiles, 32 heads), 4 waves x
// 32 q-rows; lane-local softmax state; source-swizzled global_load_lds for K
// and V^T; fused Q-RoPE; permlane pack (T12); defer-max (T13); anti-paired qt.
// EPILOGUE: grid-strided Wo fp32->bf16 conversion — hides the Wo cvt in the
// causal-load slack (early-finishing blocks convert while late blocks run).
#define CROW(r) (((r) & 3) + 8 * ((r) >> 2) + 4 * hi)
__global__ __launch_bounds__(256, 2)
void flash_attn(const unsigned short* __restrict__ qkv,
                const unsigned short* __restrict__ VT,
                const float* __restrict__ cp,
                const float* __restrict__ sp,
                unsigned short* __restrict__ Og,
                const float* __restrict__ Wo,
                unsigned short* __restrict__ woB) {
  __shared__ __align__(16) unsigned short lK[2 * 64 * 128];
  __shared__ __align__(16) unsigned short lVt[2 * 128 * 64];
  const int tid = threadIdx.x;
  const int lane = tid & 63, w = tid >> 6;
  const int l31 = lane & 31, hi = lane >> 5;
  const int h = blockIdx.y, kvh = h >> 2;
  const int qt = (h & 16) ? blockIdx.x : (15 - blockIdx.x);  // anti-paired halves
  const int nt = 2 * qt + 2;
  const int qminw = qt * 128 + w * 32;
  const int qlane = qminw + l31;
  const int qmaxw = qminw + 31;
  const float S2 = 0.12752960f;                      // (1/sqrt(128))*log2(e)

  bf16x8 qf[8];
  {
    const unsigned short* qp = qkv + (size_t)qlane * QKV_STR + h * HD + hi * 8;
#pragma unroll
    for (int ks = 0; ks < 8; ++ks) qf[ks] = *(const bf16x8*)(qp + ks * 16);
    // fused Q-RoPE: d = ks*16 + hi*8 + j (ks<4 -> d<64), pair at qf[ks+4]
    const float* crow = cp + (size_t)qlane * 128 + hi * 8;
    const float* srow = sp + (size_t)qlane * 128 + hi * 8;
#pragma unroll
    for (int ks = 0; ks < 4; ++ks) {
      float4 c0 = *(const float4*)(crow + ks * 16);
      float4 c1 = *(const float4*)(crow + ks * 16 + 4);
      float4 s0 = *(const float4*)(srow + ks * 16);
      float4 s1 = *(const float4*)(srow + ks * 16 + 4);
      float cc[8] = {c0.x, c0.y, c0.z, c0.w, c1.x, c1.y, c1.z, c1.w};
      float ss[8] = {s0.x, s0.y, s0.z, s0.w, s1.x, s1.y, s1.z, s1.w};
#pragma unroll
      for (int j = 0; j < 8; ++j) {
        float x1 = (float)qf[ks][j], x2 = (float)qf[ks + 4][j];
        qf[ks][j]     = (__bf16)(x1 * cc[j] - x2 * ss[j]);
        qf[ks + 4][j] = (__bf16)(x2 * cc[j] + x1 * ss[j]);
      }
    }
  }
  f32x16 accO[4] = {};
  float m_run = -3e38f, l_run = 0.f;

  const unsigned short* Kb0 = qkv + 4096 + kvh * HD;
  const unsigned short* VTh = VT + (size_t)kvh * 128 * S_LEN;

  auto stageK = [&](int t, int buf) {
    const unsigned short* Kb = Kb0 + (size_t)(t * 64) * QKV_STR;
    char* dst = (char*)(lK + buf * (64 * 128));
#pragma unroll
    for (int i = 0; i < 4; ++i) {
      int c = tid + i * 256;
      int row = c >> 4, s = c & 15;
      gload16(Kb + (size_t)row * QKV_STR + ((s ^ (row & 7)) * 8), dst + c * 16);
    }
  };
  auto stageV = [&](int t, int buf) {
    const unsigned short* Vb = VTh + t * 64;
    char* dst = (char*)(lVt + buf * (128 * 64));
#pragma unroll
    for (int i = 0; i < 4; ++i) {
      int c = tid + i * 256;
      int d = c >> 3, s = c & 7;
      gload16(Vb + (size_t)d * S_LEN + ((s ^ (d & 7)) * 8), dst + c * 16);
    }
  };

  stageK(0, 0);
  stageV(0, 0);
  __syncthreads();

  int cur = 0;
  for (int t = 0; t < nt; ++t) {
    const bool pf = (t + 1 < nt);
    if (pf) { stageK(t + 1, cur ^ 1); stageV(t + 1, cur ^ 1); }

#pragma unroll
    for (int c2 = 0; c2 < 2; ++c2) {
      const int kvb = t * 64 + c2 * 32;
      if (kvb > qmaxw) continue;                     // fully masked (wave-uniform)
      // QK^T: st[kv][q], lane = q, rows kv = CROW(r)
      f32x16 st = {};
      const unsigned short* lKc = lK + cur * (64 * 128) + c2 * 32 * 128;
      __builtin_amdgcn_s_setprio(1);
#pragma unroll
      for (int ks = 0; ks < 8; ++ks) {
        bf16x8 kf = *(const bf16x8*)&lKc[l31 * 128 + (((ks * 2 + hi) ^ (l31 & 7)) * 8)];
        st = __builtin_amdgcn_mfma_f32_32x32x16_bf16(kf, qf[ks], st, 0, 0, 0);
      }
      __builtin_amdgcn_s_setprio(0);
      if (kvb + 31 > qminw) {                        // diagonal: causal mask
#pragma unroll
        for (int r = 0; r < 16; ++r)
          if (kvb + CROW(r) > qlane) st[r] = -3e38f;
      }
      // online softmax: lane-local over 16 regs + partner exchange
      float t0 = fmaxf(st[0], st[1]),  t1 = fmaxf(st[2], st[3]);
      float t2 = fmaxf(st[4], st[5]),  t3 = fmaxf(st[6], st[7]);
      float t4 = fmaxf(st[8], st[9]),  t5 = fmaxf(st[10], st[11]);
      float t6 = fmaxf(st[12], st[13]), t7 = fmaxf(st[14], st[15]);
      float tm = fmaxf(fmaxf(fmaxf(t0, t1), fmaxf(t2, t3)),
                       fmaxf(fmaxf(t4, t5), fmaxf(t6, t7)));
      tm = fmaxf(tm, __shfl_xor(tm, 32));
      // defer-max (T13): skip rescale while p stays bounded by 2^8
      const bool skip = __all((tm - m_run) * S2 <= 8.0f);
      float corr = 1.f;
      if (!skip) {
        float mnew = fmaxf(m_run, tm);
        corr = __builtin_amdgcn_exp2f((m_run - mnew) * S2);
        m_run = mnew;
      }
      const float mS2 = m_run * S2;
      float p[16];
#pragma unroll
      for (int r = 0; r < 16; ++r) p[r] = __builtin_amdgcn_exp2f(st[r] * S2 - mS2);
      float s0b = (p[0] + p[1]) + (p[2] + p[3]);
      float s1b = (p[4] + p[5]) + (p[6] + p[7]);
      float s2b = (p[8] + p[9]) + (p[10] + p[11]);
      float s3b = (p[12] + p[13]) + (p[14] + p[15]);
      float rsum = (s0b + s1b) + (s2b + s3b);
      rsum += __shfl_xor(rsum, 32);
      l_run = l_run * corr + rsum;
      if (!skip) {
#pragma unroll
        for (int db = 0; db < 4; ++db) accO[db] = accO[db] * corr;   // lane-local
      }
      // pack P -> B-fragments (in-register, T12 permlane32_swap)
      unsigned wpk[8];
#pragma unroll
      for (int i = 0; i < 8; ++i) {
        __hip_bfloat162 b2 = __float22bfloat162_rn(float2{p[2 * i], p[2 * i + 1]});
        wpk[i] = *(unsigned*)&b2;
      }
      int4 pa0i, pa1i;
#if __has_builtin(__builtin_amdgcn_permlane32_swap)
      uint32x2_t r0 = __builtin_amdgcn_permlane32_swap(wpk[0], wpk[2], false, false);
      uint32x2_t r1 = __builtin_amdgcn_permlane32_swap(wpk[1], wpk[3], false, false);
      uint32x2_t r2 = __builtin_amdgcn_permlane32_swap(wpk[4], wpk[6], false, false);
      uint32x2_t r3 = __builtin_amdgcn_permlane32_swap(wpk[5], wpk[7], false, false);
      pa0i.x = (int)r0.x; pa0i.y = (int)r1.x; pa0i.z = (int)r0.y; pa0i.w = (int)r1.y;
      pa1i.x = (int)r2.x; pa1i.y = (int)r3.x; pa1i.z = (int)r2.y; pa1i.w = (int)r3.y;
#else
      unsigned xpk[8];
#pragma unroll
      for (int i = 0; i < 8; ++i) xpk[i] = (unsigned)__shfl_xor((int)wpk[i], 32);
      pa0i.x = hi ? (int)xpk[2] : (int)wpk[0]; pa0i.y = hi ? (int)xpk[3] : (int)wpk[1];
      pa0i.z = hi ? (int)wpk[2] : (int)xpk[0]; pa0i.w = hi ? (int)wpk[3] : (int)xpk[1];
      pa1i.x = hi ? (int)xpk[6] : (int)wpk[4]; pa1i.y = hi ? (int)xpk[7] : (int)wpk[5];
      pa1i.z = hi ? (int)wpk[6] : (int)xpk[4]; pa1i.w = hi ? (int)wpk[7] : (int)xpk[5];
#endif
      bf16x8 pa0 = *(bf16x8*)&pa0i, pa1 = *(bf16x8*)&pa1i;
      // PV: accO^T[d][q] += V^T[d][kv] * P[kv][q]
      const unsigned short* lVc = lVt + cur * (128 * 64);
      __builtin_amdgcn_s_setprio(1);
#pragma unroll
      for (int db = 0; db < 4; ++db) {
        int d = db * 32 + l31;
#pragma unroll
        for (int ks2 = 0; ks2 < 2; ++ks2) {
          int ck = c2 * 4 + ks2 * 2 + hi;
          bf16x8 vf = *(const bf16x8*)&lVc[d * 64 + ((ck ^ (d & 7)) * 8)];
          accO[db] = __builtin_amdgcn_mfma_f32_32x32x16_bf16(vf, ks2 ? pa1 : pa0, accO[db], 0, 0, 0);
        }
      }
      __builtin_amdgcn_s_setprio(0);
    }
    __syncthreads();   // drains vmcnt: next tile fully staged
    cur ^= 1;
  }

  // epilogue: lane owns column q; invl lane-local; packed 8B stores
  const float invl = 1.0f / l_run;
  unsigned short* orow = Og + (size_t)(qt * 128 + w * 32 + l31) * HID + h * HD;
#pragma unroll
  for (int db = 0; db < 4; ++db)
#pragma unroll
    for (int rr = 0; rr < 4; ++rr) {
      int d0 = db * 32 + rr * 8 + 4 * hi;
      ushort4 o;
      o.x = f2bf(accO[db][rr * 4 + 0] * invl);
      o.y = f2bf(accO[db][rr * 4 + 1] * invl);
      o.z = f2bf(accO[db][rr * 4 + 2] * invl);
      o.w = f2bf(accO[db][rr * 4 + 3] * invl);
      *(ushort4*)(orow + d0) = o;
    }

  // ---- Wo fp32->bf16 conversion, hidden in causal-load slack ----
  {
    const int gb = blockIdx.y * gridDim.x + blockIdx.x;   // 0..511
    const int total = HID * HID / 4;                      // 4M float4
    for (int i = gb * 256 + tid; i < total; i += 512 * 256) {
      float4 v = ((const float4*)Wo)[i];
      ushort4 o;
      o.x = f2bf(v.x); o.y = f2bf(v.y); o.z = f2bf(v.z); o.w = f2bf(v.w);
      ((ushort4*)woB)[i] = o;
    }
  }
}

// ---------------------------------------------------------------------- launch
extern "C" void kernel_launch(void* const* d_in, const int* in_sizes, int n_in,
                              void* d_out, int out_size, void* d_ws, size_t ws_size,
                              hipStream_t stream) {
  const float* hs   = (const float*)d_in[0];
  const float* cosp = (const float*)d_in[1];
  const float* sinp = (const float*)d_in[2];
  const float* Wq = (const float*)d_in[4];
  const float* Wk = (const float*)d_in[5];
  const float* Wv = (const float*)d_in[6];
  const float* Wo = (const float*)d_in[7];
  float* out = (float*)d_out;

  uint8_t* ws = (uint8_t*)d_ws;
  size_t off = 0;
  auto alloc = [&](size_t bytes) { void* p = ws + off; off += bytes; return p; };
  unsigned short* hidB  = (unsigned short*)alloc((size_t)S_LEN * HID * 2);
  unsigned short* wqkvB = (unsigned short*)alloc((size_t)QKV_STR * HID * 2);
  unsigned short* woB   = (unsigned short*)alloc((size_t)HID * HID * 2);
  unsigned short* qkvB  = (unsigned short*)alloc((size_t)S_LEN * QKV_STR * 2);
  unsigned short* aoB   = (unsigned short*)alloc((size_t)S_LEN * HID * 2);
  unsigned short* vtB   = (unsigned short*)alloc((size_t)NKVH * HD * S_LEN * 2);

  // 1. fp32 -> bf16: hidden + Wq/Wk/Wv (Wo handled inside flash_attn)
  cvt_multi<<<dim3(1024, 4), 256, 0, stream>>>(
      hs, Wq, Wk, Wv,
      hidB, wqkvB, wqkvB + (size_t)HID * HID, wqkvB + (size_t)(HID + 1024) * HID,
      S_LEN * HID / 4, HID * HID / 4, 1024 * HID / 4, 1024 * HID / 4);

  // 2. fused QKV projection: [2048][6144] = hid @ WqkvT  (R5-proven 128x128)
  gemm_bt<false><<<dim3(QKV_STR / 128, S_LEN / 128), 256, 0, stream>>>(
      hidB, wqkvB, qkvB, QKV_STR, HID);

  // 3. K-RoPE (in place) + V transpose, one launch
  rope_transpose<<<dim3(S_LEN / 128, NKVH), 256, 0, stream>>>(qkvB, cosp, sinp, vtB);

  // 4. flash attention (R9 loop, fused Q-RoPE, anti-paired qt, Wo-cvt epilogue)
  flash_attn<<<dim3(S_LEN / 128, NHEAD), 256, 0, stream>>>(
      qkvB, vtB, cosp, sinp, aoB, Wo, woB);

  // 5. output projection, fp32 straight to d_out (R5-proven 128x128)
  gemm_bt<true><<<dim3(HID / 128, S_LEN / 128), 256, 0, stream>>>(
      aoB, woB, out, HID, HID);
}

// Round 12
// 333.957 us; speedup vs baseline: 1.0133x; 1.0053x over previous
//
#include <hip/hip_runtime.h>
#include <hip/hip_bf16.h>
#include <cstdint>
#include <cstddef>

// Problem constants: B=1, S=2048, H=4096, NH=32, NKV=8, D=128, GQA group=4
#define S_LEN 2048
#define HID   4096
#define NHEAD 32
#define NKVH  8
#define HD    128
#define QKV_STR 6144   // fused qkv row stride (4096 Q + 1024 K + 1024 V)

typedef __bf16 bf16x8 __attribute__((ext_vector_type(8)));
typedef float  f32x4  __attribute__((ext_vector_type(4)));
typedef float  f32x16 __attribute__((ext_vector_type(16)));
typedef unsigned uint32x2_t __attribute__((ext_vector_type(2)));

__device__ __forceinline__ unsigned short f2bf(float f) {
  union { float f; unsigned int u; } c; c.f = f;
  unsigned int u = c.u;
  return (unsigned short)((u + 0x7fffu + ((u >> 16) & 1u)) >> 16);  // RNE
}
__device__ __forceinline__ float bf2f(unsigned short b) {
  union { unsigned int u; float f; } c; c.u = ((unsigned int)b) << 16;
  return c.f;
}
__device__ __forceinline__ void gload16(const void* g, void* l) {
  __builtin_amdgcn_global_load_lds((const __attribute__((address_space(1))) void*)g,
                                   (__attribute__((address_space(3))) void*)l, 16, 0, 0);
}

// ------------------------------------------- fp32 -> bf16, 4 segments, 1 launch
// (Wo conversion is folded into flash_attn's epilogue slack)
__global__ void cvt_multi(const float* __restrict__ s0, const float* __restrict__ s1,
                          const float* __restrict__ s2, const float* __restrict__ s3,
                          unsigned short* __restrict__ d0, unsigned short* __restrict__ d1,
                          unsigned short* __restrict__ d2, unsigned short* __restrict__ d3,
                          int n0, int n1, int n2, int n3) {
  const float* src; unsigned short* dst; int n;
  switch (blockIdx.y) {
    case 0: src = s0; dst = d0; n = n0; break;
    case 1: src = s1; dst = d1; n = n1; break;
    case 2: src = s2; dst = d2; n = n2; break;
    default: src = s3; dst = d3; n = n3; break;
  }
  int i = blockIdx.x * blockDim.x + threadIdx.x;
  int stride = gridDim.x * blockDim.x;
  for (; i < n; i += stride) {
    float4 v = ((const float4*)src)[i];
    ushort4 o;
    o.x = f2bf(v.x); o.y = f2bf(v.y); o.z = f2bf(v.z); o.w = f2bf(v.w);
    ((ushort4*)dst)[i] = o;
  }
}

// ------------------------------------------------- C[M,N] = A[M,K] * B[N,K]^T
// R5-proven structure: 128x128 tile, BK=32, 4 waves, triple-buffered LDS with
// counted vmcnt across the barrier (T3/T4); chunk swizzle (row>>1)&3 via
// pre-swizzled global source (rule #21).  M hard-coded 2048 (16 block-rows).
// EPIFUSE=1 (QKV call): K-blocks (bn 32-39) apply RoPE in the epilogue via an
// LDS-scratch pair exchange; V-blocks (bn 40-47) write transposed into VT.
// Only 16/768 blocks take the extra path — hidden in block-wave slack.
template <bool F32OUT, bool EPIFUSE>
__global__ __launch_bounds__(256)
void gemm_bt(const unsigned short* __restrict__ A,
             const unsigned short* __restrict__ Bm,
             void* __restrict__ Cout, int N, int K,
             const float* __restrict__ cp, const float* __restrict__ sp,
             unsigned short* __restrict__ VT) {
  __shared__ __align__(16) unsigned short lsmem[2 * 3 * 128 * 32];  // 48 KB
  unsigned short (*lA)[128 * 32] = (unsigned short (*)[128 * 32])lsmem;
  unsigned short (*lB)[128 * 32] = (unsigned short (*)[128 * 32])(lsmem + 3 * 128 * 32);
  const int tid = threadIdx.x;
  const int lane = tid & 63, wid = tid >> 6;
  const int l15 = lane & 15, lg = lane >> 4;
  const int wr = (wid >> 1) * 64, wc = (wid & 1) * 64;
  // XCD swizzle (nwg % 8 == 0 for both call sites), bm-fastest
  const int nwg = gridDim.x * 16;
  int bid = blockIdx.x + blockIdx.y * gridDim.x;
  bid = (bid & 7) * (nwg >> 3) + (bid >> 3);
  const int bm = bid & 15, bn = bid >> 4;

  f32x4 acc[4][4] = {};
  const unsigned short* Ab = A + (size_t)bm * 128 * K;
  const unsigned short* Bb = Bm + (size_t)bn * 128 * K;

  auto stage = [&](int t, int buf) {
    const int k0 = t * 32;
#pragma unroll
    for (int i = 0; i < 2; ++i) {     // 4 gloads/thread per tile (2 A + 2 B)
      int c = tid + i * 256;
      int row = c >> 2, sl = c & 3;
      int g = sl ^ ((row >> 1) & 3);  // inverse chunk swizzle on source
      gload16(Ab + (size_t)row * K + k0 + g * 8, (char*)lA[buf] + c * 16);
      gload16(Bb + (size_t)row * K + k0 + g * 8, (char*)lB[buf] + c * 16);
    }
  };

  const int nt = K / 32;
  stage(0, 0);
  if (nt > 1) stage(1, 1);
  const int swz = (l15 >> 1) & 3;     // read-side chunk swizzle (lane-constant)

  int cur = 0;
  for (int t = 0; t < nt; ++t) {
    if (t + 1 < nt) asm volatile("s_waitcnt vmcnt(4)" ::: "memory");
    else            asm volatile("s_waitcnt vmcnt(0)" ::: "memory");
    __builtin_amdgcn_s_barrier();
    __builtin_amdgcn_sched_barrier(0);
    if (t + 2 < nt) { int nb = cur + 2; if (nb >= 3) nb -= 3; stage(t + 2, nb); }
    bf16x8 af[4], bfr[4];
#pragma unroll
    for (int m = 0; m < 4; ++m)
      af[m] = *(const bf16x8*)&lA[cur][(wr + m * 16 + l15) * 32 + ((lg ^ swz) * 8)];
#pragma unroll
    for (int n = 0; n < 4; ++n)
      bfr[n] = *(const bf16x8*)&lB[cur][(wc + n * 16 + l15) * 32 + ((lg ^ swz) * 8)];
#pragma unroll
    for (int m = 0; m < 4; ++m)
#pragma unroll
      for (int n = 0; n < 4; ++n)
        acc[m][n] = __builtin_amdgcn_mfma_f32_16x16x32_bf16(af[m], bfr[n], acc[m][n], 0, 0, 0);
    ++cur; if (cur >= 3) cur -= 3;
  }
  // epilogue: C layout col=lane&15, row=4*(lane>>4)+reg
  const int r0 = bm * 128 + wr + 4 * lg;
  const int c0 = bn * 128 + wc + l15;

  if (EPIFUSE && bn >= 40) {
    // ---- V block: write transposed into VT[kvh][d][s] (plain [d][s] layout;
    // flash's stageV applies its own source swizzle on read)
    const int kvh = bn - 40;
#pragma unroll
    for (int n = 0; n < 4; ++n) {
      int d = wc + n * 16 + l15;
      unsigned short* vrow = VT + ((size_t)kvh * 128 + d) * S_LEN + bm * 128 + wr + 4 * lg;
#pragma unroll
      for (int m = 0; m < 4; ++m) {
        ushort4 o;
        o.x = f2bf(acc[m][n][0]); o.y = f2bf(acc[m][n][1]);
        o.z = f2bf(acc[m][n][2]); o.w = f2bf(acc[m][n][3]);
        *(ushort4*)(vrow + m * 16) = o;
      }
    }
    return;
  }
  if (EPIFUSE && bn >= 32) {
    // ---- K block: RoPE via LDS-scratch pair exchange, then write qkvB
    __syncthreads();                       // all waves done with lA/lB
    unsigned short* scr = lsmem;           // 128 x 128 bf16 = 32 KB scratch
    const int sl0 = wr + 4 * lg;           // local seq row base
#pragma unroll
    for (int m = 0; m < 4; ++m)
#pragma unroll
      for (int n = 0; n < 4; ++n) {
        int d = wc + n * 16 + l15;
#pragma unroll
        for (int j = 0; j < 4; ++j)
          scr[(sl0 + m * 16 + j) * 128 + d] = f2bf(acc[m][n][j]);
      }
    __syncthreads();
#pragma unroll
    for (int m = 0; m < 4; ++m)
#pragma unroll
      for (int n = 0; n < 4; ++n) {
        int d = wc + n * 16 + l15;
#pragma unroll
        for (int j = 0; j < 4; ++j) {
          int sl = sl0 + m * 16 + j;
          float x = bf2f(scr[sl * 128 + d]);
          float pr = bf2f(scr[sl * 128 + (d ^ 64)]);
          size_t crow = (size_t)(bm * 128 + sl) * 128 + (d & 63);
          float c = cp[crow], sn = sp[crow];
          float o = (d < 64) ? (x * c - pr * sn) : (x * c + pr * sn);
          ((unsigned short*)Cout)[(size_t)(bm * 128 + sl) * N + bn * 128 + d] = f2bf(o);
        }
      }
    return;
  }
  // ---- plain C write (Q blocks / Wo GEMM)
#pragma unroll
  for (int m = 0; m < 4; ++m)
#pragma unroll
    for (int n = 0; n < 4; ++n)
#pragma unroll
      for (int j = 0; j < 4; ++j) {
        size_t idx = (size_t)(r0 + m * 16 + j) * N + (c0 + n * 16);
        if (F32OUT) ((float*)Cout)[idx] = acc[m][n][j];
        else        ((unsigned short*)Cout)[idx] = f2bf(acc[m][n][j]);
      }
}

// ------------------------------------------------------------ flash attention
// Swapped-QK^T 32x32 (R9-proven loop): grid (16 qtiles, 32 heads), 4 waves x
// 32 q-rows; lane-local softmax state; source-swizzled global_load_lds for K
// and V^T; fused Q-RoPE; permlane pack (T12); defer-max (T13); anti-paired qt.
// EPILOGUE: grid-strided Wo fp32->bf16 conversion (hidden in load slack).
#define CROW(r) (((r) & 3) + 8 * ((r) >> 2) + 4 * hi)
__global__ __launch_bounds__(256, 2)
void flash_attn(const unsigned short* __restrict__ qkv,
                const unsigned short* __restrict__ VT,
                const float* __restrict__ cp,
                const float* __restrict__ sp,
                unsigned short* __restrict__ Og,
                const float* __restrict__ Wo,
                unsigned short* __restrict__ woB) {
  __shared__ __align__(16) unsigned short lK[2 * 64 * 128];
  __shared__ __align__(16) unsigned short lVt[2 * 128 * 64];
  const int tid = threadIdx.x;
  const int lane = tid & 63, w = tid >> 6;
  const int l31 = lane & 31, hi = lane >> 5;
  const int h = blockIdx.y, kvh = h >> 2;
  const int qt = (h & 16) ? blockIdx.x : (15 - blockIdx.x);  // anti-paired halves
  const int nt = 2 * qt + 2;
  const int qminw = qt * 128 + w * 32;
  const int qlane = qminw + l31;
  const int qmaxw = qminw + 31;
  const float S2 = 0.12752960f;                      // (1/sqrt(128))*log2(e)

  bf16x8 qf[8];
  {
    const unsigned short* qp = qkv + (size_t)qlane * QKV_STR + h * HD + hi * 8;
#pragma unroll
    for (int ks = 0; ks < 8; ++ks) qf[ks] = *(const bf16x8*)(qp + ks * 16);
    // fused Q-RoPE: d = ks*16 + hi*8 + j (ks<4 -> d<64), pair at qf[ks+4]
    const float* crow = cp + (size_t)qlane * 128 + hi * 8;
    const float* srow = sp + (size_t)qlane * 128 + hi * 8;
#pragma unroll
    for (int ks = 0; ks < 4; ++ks) {
      float4 c0 = *(const float4*)(crow + ks * 16);
      float4 c1 = *(const float4*)(crow + ks * 16 + 4);
      float4 s0 = *(const float4*)(srow + ks * 16);
      float4 s1 = *(const float4*)(srow + ks * 16 + 4);
      float cc[8] = {c0.x, c0.y, c0.z, c0.w, c1.x, c1.y, c1.z, c1.w};
      float ss[8] = {s0.x, s0.y, s0.z, s0.w, s1.x, s1.y, s1.z, s1.w};
#pragma unroll
      for (int j = 0; j < 8; ++j) {
        float x1 = (float)qf[ks][j], x2 = (float)qf[ks + 4][j];
        qf[ks][j]     = (__bf16)(x1 * cc[j] - x2 * ss[j]);
        qf[ks + 4][j] = (__bf16)(x2 * cc[j] + x1 * ss[j]);
      }
    }
  }
  f32x16 accO[4] = {};
  float m_run = -3e38f, l_run = 0.f;

  const unsigned short* Kb0 = qkv + 4096 + kvh * HD;
  const unsigned short* VTh = VT + (size_t)kvh * 128 * S_LEN;

  auto stageK = [&](int t, int buf) {
    const unsigned short* Kb = Kb0 + (size_t)(t * 64) * QKV_STR;
    char* dst = (char*)(lK + buf * (64 * 128));
#pragma unroll
    for (int i = 0; i < 4; ++i) {
      int c = tid + i * 256;
      int row = c >> 4, s = c & 15;
      gload16(Kb + (size_t)row * QKV_STR + ((s ^ (row & 7)) * 8), dst + c * 16);
    }
  };
  auto stageV = [&](int t, int buf) {
    const unsigned short* Vb = VTh + t * 64;
    char* dst = (char*)(lVt + buf * (128 * 64));
#pragma unroll
    for (int i = 0; i < 4; ++i) {
      int c = tid + i * 256;
      int d = c >> 3, s = c & 7;
      gload16(Vb + (size_t)d * S_LEN + ((s ^ (d & 7)) * 8), dst + c * 16);
    }
  };

  stageK(0, 0);
  stageV(0, 0);
  __syncthreads();

  int cur = 0;
  for (int t = 0; t < nt; ++t) {
    const bool pf = (t + 1 < nt);
    if (pf) { stageK(t + 1, cur ^ 1); stageV(t + 1, cur ^ 1); }

#pragma unroll
    for (int c2 = 0; c2 < 2; ++c2) {
      const int kvb = t * 64 + c2 * 32;
      if (kvb > qmaxw) continue;                     // fully masked (wave-uniform)
      // QK^T: st[kv][q], lane = q, rows kv = CROW(r)
      f32x16 st = {};
      const unsigned short* lKc = lK + cur * (64 * 128) + c2 * 32 * 128;
      __builtin_amdgcn_s_setprio(1);
#pragma unroll
      for (int ks = 0; ks < 8; ++ks) {
        bf16x8 kf = *(const bf16x8*)&lKc[l31 * 128 + (((ks * 2 + hi) ^ (l31 & 7)) * 8)];
        st = __builtin_amdgcn_mfma_f32_32x32x16_bf16(kf, qf[ks], st, 0, 0, 0);
      }
      __builtin_amdgcn_s_setprio(0);
      if (kvb + 31 > qminw) {                        // diagonal: causal mask
#pragma unroll
        for (int r = 0; r < 16; ++r)
          if (kvb + CROW(r) > qlane) st[r] = -3e38f;
      }
      // online softmax: lane-local over 16 regs + partner exchange
      float t0 = fmaxf(st[0], st[1]),  t1 = fmaxf(st[2], st[3]);
      float t2 = fmaxf(st[4], st[5]),  t3 = fmaxf(st[6], st[7]);
      float t4 = fmaxf(st[8], st[9]),  t5 = fmaxf(st[10], st[11]);
      float t6 = fmaxf(st[12], st[13]), t7 = fmaxf(st[14], st[15]);
      float tm = fmaxf(fmaxf(fmaxf(t0, t1), fmaxf(t2, t3)),
                       fmaxf(fmaxf(t4, t5), fmaxf(t6, t7)));
      tm = fmaxf(tm, __shfl_xor(tm, 32));
      // defer-max (T13): skip rescale while p stays bounded by 2^8
      const bool skip = __all((tm - m_run) * S2 <= 8.0f);
      float corr = 1.f;
      if (!skip) {
        float mnew = fmaxf(m_run, tm);
        corr = __builtin_amdgcn_exp2f((m_run - mnew) * S2);
        m_run = mnew;
      }
      const float mS2 = m_run * S2;
      float p[16];
#pragma unroll
      for (int r = 0; r < 16; ++r) p[r] = __builtin_amdgcn_exp2f(st[r] * S2 - mS2);
      float s0b = (p[0] + p[1]) + (p[2] + p[3]);
      float s1b = (p[4] + p[5]) + (p[6] + p[7]);
      float s2b = (p[8] + p[9]) + (p[10] + p[11]);
      float s3b = (p[12] + p[13]) + (p[14] + p[15]);
      float rsum = (s0b + s1b) + (s2b + s3b);
      rsum += __shfl_xor(rsum, 32);
      l_run = l_run * corr + rsum;
      if (!skip) {
#pragma unroll
        for (int db = 0; db < 4; ++db) accO[db] = accO[db] * corr;   // lane-local
      }
      // pack P -> B-fragments (in-register, T12 permlane32_swap)
      unsigned wpk[8];
#pragma unroll
      for (int i = 0; i < 8; ++i) {
        __hip_bfloat162 b2 = __float22bfloat162_rn(float2{p[2 * i], p[2 * i + 1]});
        wpk[i] = *(unsigned*)&b2;
      }
      int4 pa0i, pa1i;
#if __has_builtin(__builtin_amdgcn_permlane32_swap)
      uint32x2_t r0 = __builtin_amdgcn_permlane32_swap(wpk[0], wpk[2], false, false);
      uint32x2_t r1 = __builtin_amdgcn_permlane32_swap(wpk[1], wpk[3], false, false);
      uint32x2_t r2 = __builtin_amdgcn_permlane32_swap(wpk[4], wpk[6], false, false);
      uint32x2_t r3 = __builtin_amdgcn_permlane32_swap(wpk[5], wpk[7], false, false);
      pa0i.x = (int)r0.x; pa0i.y = (int)r1.x; pa0i.z = (int)r0.y; pa0i.w = (int)r1.y;
      pa1i.x = (int)r2.x; pa1i.y = (int)r3.x; pa1i.z = (int)r2.y; pa1i.w = (int)r3.y;
#else
      unsigned xpk[8];
#pragma unroll
      for (int i = 0; i < 8; ++i) xpk[i] = (unsigned)__shfl_xor((int)wpk[i], 32);
      pa0i.x = hi ? (int)xpk[2] : (int)wpk[0]; pa0i.y = hi ? (int)xpk[3] : (int)wpk[1];
      pa0i.z = hi ? (int)wpk[2] : (int)xpk[0]; pa0i.w = hi ? (int)wpk[3] : (int)xpk[1];
      pa1i.x = hi ? (int)xpk[6] : (int)wpk[4]; pa1i.y = hi ? (int)xpk[7] : (int)wpk[5];
      pa1i.z = hi ? (int)wpk[6] : (int)xpk[4]; pa1i.w = hi ? (int)wpk[7] : (int)xpk[5];
#endif
      bf16x8 pa0 = *(bf16x8*)&pa0i, pa1 = *(bf16x8*)&pa1i;
      // PV: accO^T[d][q] += V^T[d][kv] * P[kv][q]
      const unsigned short* lVc = lVt + cur * (128 * 64);
      __builtin_amdgcn_s_setprio(1);
#pragma unroll
      for (int db = 0; db < 4; ++db) {
        int d = db * 32 + l31;
#pragma unroll
        for (int ks2 = 0; ks2 < 2; ++ks2) {
          int ck = c2 * 4 + ks2 * 2 + hi;
          bf16x8 vf = *(const bf16x8*)&lVc[d * 64 + ((ck ^ (d & 7)) * 8)];
          accO[db] = __builtin_amdgcn_mfma_f32_32x32x16_bf16(vf, ks2 ? pa1 : pa0, accO[db], 0, 0, 0);
        }
      }
      __builtin_amdgcn_s_setprio(0);
    }
    __syncthreads();   // drains vmcnt: next tile fully staged
    cur ^= 1;
  }

  // epilogue: lane owns column q; invl lane-local; packed 8B stores
  const float invl = 1.0f / l_run;
  unsigned short* orow = Og + (size_t)(qt * 128 + w * 32 + l31) * HID + h * HD;
#pragma unroll
  for (int db = 0; db < 4; ++db)
#pragma unroll
    for (int rr = 0; rr < 4; ++rr) {
      int d0 = db * 32 + rr * 8 + 4 * hi;
      ushort4 o;
      o.x = f2bf(accO[db][rr * 4 + 0] * invl);
      o.y = f2bf(accO[db][rr * 4 + 1] * invl);
      o.z = f2bf(accO[db][rr * 4 + 2] * invl);
      o.w = f2bf(accO[db][rr * 4 + 3] * invl);
      *(ushort4*)(orow + d0) = o;
    }

  // ---- Wo fp32->bf16 conversion, hidden in causal-load slack ----
  {
    const int gb = blockIdx.y * gridDim.x + blockIdx.x;   // 0..511
    const int total = HID * HID / 4;                      // 4M float4
    for (int i = gb * 256 + tid; i < total; i += 512 * 256) {
      float4 v = ((const float4*)Wo)[i];
      ushort4 o;
      o.x = f2bf(v.x); o.y = f2bf(v.y); o.z = f2bf(v.z); o.w = f2bf(v.w);
      ((ushort4*)woB)[i] = o;
    }
  }
}

// ---------------------------------------------------------------------- launch
extern "C" void kernel_launch(void* const* d_in, const int* in_sizes, int n_in,
                              void* d_out, int out_size, void* d_ws, size_t ws_size,
                              hipStream_t stream) {
  const float* hs   = (const float*)d_in[0];
  const float* cosp = (const float*)d_in[1];
  const float* sinp = (const float*)d_in[2];
  const float* Wq = (const float*)d_in[4];
  const float* Wk = (const float*)d_in[5];
  const float* Wv = (const float*)d_in[6];
  const float* Wo = (const float*)d_in[7];
  float* out = (float*)d_out;

  uint8_t* ws = (uint8_t*)d_ws;
  size_t off = 0;
  auto alloc = [&](size_t bytes) { void* p = ws + off; off += bytes; return p; };
  unsigned short* hidB  = (unsigned short*)alloc((size_t)S_LEN * HID * 2);
  unsigned short* wqkvB = (unsigned short*)alloc((size_t)QKV_STR * HID * 2);
  unsigned short* woB   = (unsigned short*)alloc((size_t)HID * HID * 2);
  unsigned short* qkvB  = (unsigned short*)alloc((size_t)S_LEN * QKV_STR * 2);
  unsigned short* aoB   = (unsigned short*)alloc((size_t)S_LEN * HID * 2);
  unsigned short* vtB   = (unsigned short*)alloc((size_t)NKVH * HD * S_LEN * 2);

  // 1. fp32 -> bf16: hidden + Wq/Wk/Wv (Wo handled inside flash_attn)
  cvt_multi<<<dim3(1024, 4), 256, 0, stream>>>(
      hs, Wq, Wk, Wv,
      hidB, wqkvB, wqkvB + (size_t)HID * HID, wqkvB + (size_t)(HID + 1024) * HID,
      S_LEN * HID / 4, HID * HID / 4, 1024 * HID / 4, 1024 * HID / 4);

  // 2. fused QKV projection with in-epilogue K-RoPE and V-transpose
  gemm_bt<false, true><<<dim3(QKV_STR / 128, S_LEN / 128), 256, 0, stream>>>(
      hidB, wqkvB, qkvB, QKV_STR, HID, cosp, sinp, vtB);

  // 3. flash attention (R9 loop, fused Q-RoPE, anti-paired qt, Wo-cvt epilogue)
  flash_attn<<<dim3(S_LEN / 128, NHEAD), 256, 0, stream>>>(
      qkvB, vtB, cosp, sinp, aoB, Wo, woB);

  // 4. output projection, fp32 straight to d_out (R5-proven 128x128)
  gemm_bt<true, false><<<dim3(HID / 128, S_LEN / 128), 256, 0, stream>>>(
      aoB, woB, out, HID, HID, nullptr, nullptr, nullptr);
}

// Round 13
// 329.351 us; speedup vs baseline: 1.0275x; 1.0140x over previous
//
#include <hip/hip_runtime.h>
#include <hip/hip_bf16.h>
#include <cstdint>
#include <cstddef>

// Problem constants: B=1, S=2048, H=4096, NH=32, NKV=8, D=128, GQA group=4
#define S_LEN 2048
#define HID   4096
#define NHEAD 32
#define NKVH  8
#define HD    128
#define QKV_STR 6144   // fused qkv row stride (4096 Q + 1024 K + 1024 V)

typedef __bf16 bf16x8 __attribute__((ext_vector_type(8)));
typedef float  f32x4  __attribute__((ext_vector_type(4)));
typedef float  f32x16 __attribute__((ext_vector_type(16)));
typedef unsigned uint32x2_t __attribute__((ext_vector_type(2)));

__device__ __forceinline__ unsigned short f2bf(float f) {
  union { float f; unsigned int u; } c; c.f = f;
  unsigned int u = c.u;
  return (unsigned short)((u + 0x7fffu + ((u >> 16) & 1u)) >> 16);  // RNE
}
__device__ __forceinline__ float bf2f(unsigned short b) {
  union { unsigned int u; float f; } c; c.u = ((unsigned int)b) << 16;
  return c.f;
}
__device__ __forceinline__ void gload16(const void* g, void* l) {
  __builtin_amdgcn_global_load_lds((const __attribute__((address_space(1))) void*)g,
                                   (__attribute__((address_space(3))) void*)l, 16, 0, 0);
}

// ------------------------------------------- fp32 -> bf16, 4 segments, 1 launch
// (Wo conversion is folded into flash_attn's epilogue slack)
__global__ void cvt_multi(const float* __restrict__ s0, const float* __restrict__ s1,
                          const float* __restrict__ s2, const float* __restrict__ s3,
                          unsigned short* __restrict__ d0, unsigned short* __restrict__ d1,
                          unsigned short* __restrict__ d2, unsigned short* __restrict__ d3,
                          int n0, int n1, int n2, int n3) {
  const float* src; unsigned short* dst; int n;
  switch (blockIdx.y) {
    case 0: src = s0; dst = d0; n = n0; break;
    case 1: src = s1; dst = d1; n = n1; break;
    case 2: src = s2; dst = d2; n = n2; break;
    default: src = s3; dst = d3; n = n3; break;
  }
  int i = blockIdx.x * blockDim.x + threadIdx.x;
  int stride = gridDim.x * blockDim.x;
  for (; i < n; i += stride) {
    float4 v = ((const float4*)src)[i];
    ushort4 o;
    o.x = f2bf(v.x); o.y = f2bf(v.y); o.z = f2bf(v.z); o.w = f2bf(v.w);
    ((ushort4*)dst)[i] = o;
  }
}

// ------------------------------------------------- C[M,N] = A[M,K] * B[N,K]^T
// R5-proven structure: 128x128 tile, BK=32, 4 waves, triple-buffered LDS with
// counted vmcnt across the barrier (T3/T4); chunk swizzle (row>>1)&3 via
// pre-swizzled global source (rule #21).  SEPARATE lA/lB arrays (compile-time
// LDS offsets — R12's union-pointer refactor cost +32 VGPR and halved
// occupancy).  M hard-coded 2048 (16 block-rows).
// EPIFUSE (QKV call): K-blocks (bn 32-39) do RoPE via a lean LDS pair
// exchange (wc=64 waves publish 16KB to lA scratch; wc=0 waves write both
// halves); V-blocks (bn 40-47) write transposed into VT.  16/768 blocks.
template <bool F32OUT, bool EPIFUSE>
__global__ __launch_bounds__(256)
void gemm_bt(const unsigned short* __restrict__ A,
             const unsigned short* __restrict__ Bm,
             void* __restrict__ Cout, int N, int K,
             const float* __restrict__ cp, const float* __restrict__ sp,
             unsigned short* __restrict__ VT) {
  __shared__ __align__(16) unsigned short lA[3][128 * 32];
  __shared__ __align__(16) unsigned short lB[3][128 * 32];
  const int tid = threadIdx.x;
  const int lane = tid & 63, wid = tid >> 6;
  const int l15 = lane & 15, lg = lane >> 4;
  const int wr = (wid >> 1) * 64, wc = (wid & 1) * 64;
  // XCD swizzle (nwg % 8 == 0 for both call sites), bm-fastest
  const int nwg = gridDim.x * 16;
  int bid = blockIdx.x + blockIdx.y * gridDim.x;
  bid = (bid & 7) * (nwg >> 3) + (bid >> 3);
  const int bm = bid & 15, bn = bid >> 4;

  f32x4 acc[4][4] = {};
  const unsigned short* Ab = A + (size_t)bm * 128 * K;
  const unsigned short* Bb = Bm + (size_t)bn * 128 * K;

  auto stage = [&](int t, int buf) {
    const int k0 = t * 32;
#pragma unroll
    for (int i = 0; i < 2; ++i) {     // 4 gloads/thread per tile (2 A + 2 B)
      int c = tid + i * 256;
      int row = c >> 2, sl = c & 3;
      int g = sl ^ ((row >> 1) & 3);  // inverse chunk swizzle on source
      gload16(Ab + (size_t)row * K + k0 + g * 8, (char*)lA[buf] + c * 16);
      gload16(Bb + (size_t)row * K + k0 + g * 8, (char*)lB[buf] + c * 16);
    }
  };

  const int nt = K / 32;
  stage(0, 0);
  if (nt > 1) stage(1, 1);
  const int swz = (l15 >> 1) & 3;     // read-side chunk swizzle (lane-constant)

  int cur = 0;
  for (int t = 0; t < nt; ++t) {
    if (t + 1 < nt) asm volatile("s_waitcnt vmcnt(4)" ::: "memory");
    else            asm volatile("s_waitcnt vmcnt(0)" ::: "memory");
    __builtin_amdgcn_s_barrier();
    __builtin_amdgcn_sched_barrier(0);
    if (t + 2 < nt) { int nb = cur + 2; if (nb >= 3) nb -= 3; stage(t + 2, nb); }
    bf16x8 af[4], bfr[4];
#pragma unroll
    for (int m = 0; m < 4; ++m)
      af[m] = *(const bf16x8*)&lA[cur][(wr + m * 16 + l15) * 32 + ((lg ^ swz) * 8)];
#pragma unroll
    for (int n = 0; n < 4; ++n)
      bfr[n] = *(const bf16x8*)&lB[cur][(wc + n * 16 + l15) * 32 + ((lg ^ swz) * 8)];
#pragma unroll
    for (int m = 0; m < 4; ++m)
#pragma unroll
      for (int n = 0; n < 4; ++n)
        acc[m][n] = __builtin_amdgcn_mfma_f32_16x16x32_bf16(af[m], bfr[n], acc[m][n], 0, 0, 0);
    ++cur; if (cur >= 3) cur -= 3;
  }

  if constexpr (EPIFUSE) {
    if (bn >= 40) {
      // ---- V block: write transposed into VT[kvh][d][s] (plain [d][s];
      // flash's stageV applies its own source swizzle on read)
      const int kvh = bn - 40;
#pragma unroll
      for (int n = 0; n < 4; ++n) {
        int d = wc + n * 16 + l15;
        unsigned short* vrow = VT + ((size_t)kvh * 128 + d) * S_LEN + bm * 128 + wr + 4 * lg;
#pragma unroll
        for (int m = 0; m < 4; ++m) {
          ushort4 o;
          o.x = f2bf(acc[m][n][0]); o.y = f2bf(acc[m][n][1]);
          o.z = f2bf(acc[m][n][2]); o.w = f2bf(acc[m][n][3]);
          *(ushort4*)(vrow + m * 16) = o;
        }
      }
      return;
    }
    if (bn >= 32) {
      // ---- K block: RoPE epilogue.  wc=64 waves publish their 64x64 tile
      // (rows wr..wr+63, cols 64..127) to 16 KB scratch in lA; wc=0 waves
      // then compute BOTH rotated halves (own x1 stays f32) and write.
      __syncthreads();                       // main-loop LDS reads complete
      unsigned short* scr = (unsigned short*)lA;   // 128 x 64 bf16 = 16 KB
      if (wc == 64) {
#pragma unroll
        for (int m = 0; m < 4; ++m)
#pragma unroll
          for (int n = 0; n < 4; ++n) {
            int dc = n * 16 + l15;           // col - 64
#pragma unroll
            for (int j = 0; j < 4; ++j)
              scr[(wr + 4 * lg + m * 16 + j) * 64 + dc] = f2bf(acc[m][n][j]);
          }
      }
      __syncthreads();
      if (wc == 0) {
        unsigned short* Co = (unsigned short*)Cout;
#pragma unroll
        for (int m = 0; m < 4; ++m)
#pragma unroll
          for (int n = 0; n < 4; ++n) {
            int d = n * 16 + l15;            // 0..63
#pragma unroll
            for (int j = 0; j < 4; ++j) {
              int sl = wr + 4 * lg + m * 16 + j;
              float x1 = acc[m][n][j];
              float x2 = bf2f(scr[sl * 64 + d]);
              size_t crow = (size_t)(bm * 128 + sl) * 128 + d;
              float c = cp[crow], sn = sp[crow];
              size_t orow = (size_t)(bm * 128 + sl) * N + bn * 128 + d;
              Co[orow]      = f2bf(x1 * c - x2 * sn);
              Co[orow + 64] = f2bf(x2 * c + x1 * sn);
            }
          }
      }
      return;
    }
  }
  // ---- plain C write (Q blocks / Wo GEMM): col=lane&15, row=4*(lane>>4)+reg
  const int r0 = bm * 128 + wr + 4 * lg;
  const int c0 = bn * 128 + wc + l15;
#pragma unroll
  for (int m = 0; m < 4; ++m)
#pragma unroll
    for (int n = 0; n < 4; ++n)
#pragma unroll
      for (int j = 0; j < 4; ++j) {
        size_t idx = (size_t)(r0 + m * 16 + j) * N + (c0 + n * 16);
        if (F32OUT) ((float*)Cout)[idx] = acc[m][n][j];
        else        ((unsigned short*)Cout)[idx] = f2bf(acc[m][n][j]);
      }
}

// ------------------------------------------------------------ flash attention
// Swapped-QK^T 32x32 (R9-proven loop): grid (16 qtiles, 32 heads), 4 waves x
// 32 q-rows; lane-local softmax state; source-swizzled global_load_lds for K
// and V^T; fused Q-RoPE; permlane pack (T12); defer-max (T13); anti-paired qt.
// EPILOGUE: grid-strided Wo fp32->bf16 conversion (hidden in load slack).
#define CROW(r) (((r) & 3) + 8 * ((r) >> 2) + 4 * hi)
__global__ __launch_bounds__(256, 2)
void flash_attn(const unsigned short* __restrict__ qkv,
                const unsigned short* __restrict__ VT,
                const float* __restrict__ cp,
                const float* __restrict__ sp,
                unsigned short* __restrict__ Og,
                const float* __restrict__ Wo,
                unsigned short* __restrict__ woB) {
  __shared__ __align__(16) unsigned short lK[2 * 64 * 128];
  __shared__ __align__(16) unsigned short lVt[2 * 128 * 64];
  const int tid = threadIdx.x;
  const int lane = tid & 63, w = tid >> 6;
  const int l31 = lane & 31, hi = lane >> 5;
  const int h = blockIdx.y, kvh = h >> 2;
  const int qt = (h & 16) ? blockIdx.x : (15 - blockIdx.x);  // anti-paired halves
  const int nt = 2 * qt + 2;
  const int qminw = qt * 128 + w * 32;
  const int qlane = qminw + l31;
  const int qmaxw = qminw + 31;
  const float S2 = 0.12752960f;                      // (1/sqrt(128))*log2(e)

  bf16x8 qf[8];
  {
    const unsigned short* qp = qkv + (size_t)qlane * QKV_STR + h * HD + hi * 8;
#pragma unroll
    for (int ks = 0; ks < 8; ++ks) qf[ks] = *(const bf16x8*)(qp + ks * 16);
    // fused Q-RoPE: d = ks*16 + hi*8 + j (ks<4 -> d<64), pair at qf[ks+4]
    const float* crow = cp + (size_t)qlane * 128 + hi * 8;
    const float* srow = sp + (size_t)qlane * 128 + hi * 8;
#pragma unroll
    for (int ks = 0; ks < 4; ++ks) {
      float4 c0 = *(const float4*)(crow + ks * 16);
      float4 c1 = *(const float4*)(crow + ks * 16 + 4);
      float4 s0 = *(const float4*)(srow + ks * 16);
      float4 s1 = *(const float4*)(srow + ks * 16 + 4);
      float cc[8] = {c0.x, c0.y, c0.z, c0.w, c1.x, c1.y, c1.z, c1.w};
      float ss[8] = {s0.x, s0.y, s0.z, s0.w, s1.x, s1.y, s1.z, s1.w};
#pragma unroll
      for (int j = 0; j < 8; ++j) {
        float x1 = (float)qf[ks][j], x2 = (float)qf[ks + 4][j];
        qf[ks][j]     = (__bf16)(x1 * cc[j] - x2 * ss[j]);
        qf[ks + 4][j] = (__bf16)(x2 * cc[j] + x1 * ss[j]);
      }
    }
  }
  f32x16 accO[4] = {};
  float m_run = -3e38f, l_run = 0.f;

  const unsigned short* Kb0 = qkv + 4096 + kvh * HD;
  const unsigned short* VTh = VT + (size_t)kvh * 128 * S_LEN;

  auto stageK = [&](int t, int buf) {
    const unsigned short* Kb = Kb0 + (size_t)(t * 64) * QKV_STR;
    char* dst = (char*)(lK + buf * (64 * 128));
#pragma unroll
    for (int i = 0; i < 4; ++i) {
      int c = tid + i * 256;
      int row = c >> 4, s = c & 15;
      gload16(Kb + (size_t)row * QKV_STR + ((s ^ (row & 7)) * 8), dst + c * 16);
    }
  };
  auto stageV = [&](int t, int buf) {
    const unsigned short* Vb = VTh + t * 64;
    char* dst = (char*)(lVt + buf * (128 * 64));
#pragma unroll
    for (int i = 0; i < 4; ++i) {
      int c = tid + i * 256;
      int d = c >> 3, s = c & 7;
      gload16(Vb + (size_t)d * S_LEN + ((s ^ (d & 7)) * 8), dst + c * 16);
    }
  };

  stageK(0, 0);
  stageV(0, 0);
  __syncthreads();

  int cur = 0;
  for (int t = 0; t < nt; ++t) {
    const bool pf = (t + 1 < nt);
    if (pf) { stageK(t + 1, cur ^ 1); stageV(t + 1, cur ^ 1); }

#pragma unroll
    for (int c2 = 0; c2 < 2; ++c2) {
      const int kvb = t * 64 + c2 * 32;
      if (kvb > qmaxw) continue;                     // fully masked (wave-uniform)
      // QK^T: st[kv][q], lane = q, rows kv = CROW(r)
      f32x16 st = {};
      const unsigned short* lKc = lK + cur * (64 * 128) + c2 * 32 * 128;
      __builtin_amdgcn_s_setprio(1);
#pragma unroll
      for (int ks = 0; ks < 8; ++ks) {
        bf16x8 kf = *(const bf16x8*)&lKc[l31 * 128 + (((ks * 2 + hi) ^ (l31 & 7)) * 8)];
        st = __builtin_amdgcn_mfma_f32_32x32x16_bf16(kf, qf[ks], st, 0, 0, 0);
      }
      __builtin_amdgcn_s_setprio(0);
      if (kvb + 31 > qminw) {                        // diagonal: causal mask
#pragma unroll
        for (int r = 0; r < 16; ++r)
          if (kvb + CROW(r) > qlane) st[r] = -3e38f;
      }
      // online softmax: lane-local over 16 regs + partner exchange
      float t0 = fmaxf(st[0], st[1]),  t1 = fmaxf(st[2], st[3]);
      float t2 = fmaxf(st[4], st[5]),  t3 = fmaxf(st[6], st[7]);
      float t4 = fmaxf(st[8], st[9]),  t5 = fmaxf(st[10], st[11]);
      float t6 = fmaxf(st[12], st[13]), t7 = fmaxf(st[14], st[15]);
      float tm = fmaxf(fmaxf(fmaxf(t0, t1), fmaxf(t2, t3)),
                       fmaxf(fmaxf(t4, t5), fmaxf(t6, t7)));
      tm = fmaxf(tm, __shfl_xor(tm, 32));
      // defer-max (T13): skip rescale while p stays bounded by 2^8
      const bool skip = __all((tm - m_run) * S2 <= 8.0f);
      float corr = 1.f;
      if (!skip) {
        float mnew = fmaxf(m_run, tm);
        corr = __builtin_amdgcn_exp2f((m_run - mnew) * S2);
        m_run = mnew;
      }
      const float mS2 = m_run * S2;
      float p[16];
#pragma unroll
      for (int r = 0; r < 16; ++r) p[r] = __builtin_amdgcn_exp2f(st[r] * S2 - mS2);
      float s0b = (p[0] + p[1]) + (p[2] + p[3]);
      float s1b = (p[4] + p[5]) + (p[6] + p[7]);
      float s2b = (p[8] + p[9]) + (p[10] + p[11]);
      float s3b = (p[12] + p[13]) + (p[14] + p[15]);
      float rsum = (s0b + s1b) + (s2b + s3b);
      rsum += __shfl_xor(rsum, 32);
      l_run = l_run * corr + rsum;
      if (!skip) {
#pragma unroll
        for (int db = 0; db < 4; ++db) accO[db] = accO[db] * corr;   // lane-local
      }
      // pack P -> B-fragments (in-register, T12 permlane32_swap)
      unsigned wpk[8];
#pragma unroll
      for (int i = 0; i < 8; ++i) {
        __hip_bfloat162 b2 = __float22bfloat162_rn(float2{p[2 * i], p[2 * i + 1]});
        wpk[i] = *(unsigned*)&b2;
      }
      int4 pa0i, pa1i;
#if __has_builtin(__builtin_amdgcn_permlane32_swap)
      uint32x2_t r0 = __builtin_amdgcn_permlane32_swap(wpk[0], wpk[2], false, false);
      uint32x2_t r1 = __builtin_amdgcn_permlane32_swap(wpk[1], wpk[3], false, false);
      uint32x2_t r2 = __builtin_amdgcn_permlane32_swap(wpk[4], wpk[6], false, false);
      uint32x2_t r3 = __builtin_amdgcn_permlane32_swap(wpk[5], wpk[7], false, false);
      pa0i.x = (int)r0.x; pa0i.y = (int)r1.x; pa0i.z = (int)r0.y; pa0i.w = (int)r1.y;
      pa1i.x = (int)r2.x; pa1i.y = (int)r3.x; pa1i.z = (int)r2.y; pa1i.w = (int)r3.y;
#else
      unsigned xpk[8];
#pragma unroll
      for (int i = 0; i < 8; ++i) xpk[i] = (unsigned)__shfl_xor((int)wpk[i], 32);
      pa0i.x = hi ? (int)xpk[2] : (int)wpk[0]; pa0i.y = hi ? (int)xpk[3] : (int)wpk[1];
      pa0i.z = hi ? (int)wpk[2] : (int)xpk[0]; pa0i.w = hi ? (int)wpk[3] : (int)xpk[1];
      pa1i.x = hi ? (int)xpk[6] : (int)wpk[4]; pa1i.y = hi ? (int)xpk[7] : (int)wpk[5];
      pa1i.z = hi ? (int)wpk[6] : (int)xpk[4]; pa1i.w = hi ? (int)wpk[7] : (int)xpk[5];
#endif
      bf16x8 pa0 = *(bf16x8*)&pa0i, pa1 = *(bf16x8*)&pa1i;
      // PV: accO^T[d][q] += V^T[d][kv] * P[kv][q]
      const unsigned short* lVc = lVt + cur * (128 * 64);
      __builtin_amdgcn_s_setprio(1);
#pragma unroll
      for (int db = 0; db < 4; ++db) {
        int d = db * 32 + l31;
#pragma unroll
        for (int ks2 = 0; ks2 < 2; ++ks2) {
          int ck = c2 * 4 + ks2 * 2 + hi;
          bf16x8 vf = *(const bf16x8*)&lVc[d * 64 + ((ck ^ (d & 7)) * 8)];
          accO[db] = __builtin_amdgcn_mfma_f32_32x32x16_bf16(vf, ks2 ? pa1 : pa0, accO[db], 0, 0, 0);
        }
      }
      __builtin_amdgcn_s_setprio(0);
    }
    __syncthreads();   // drains vmcnt: next tile fully staged
    cur ^= 1;
  }

  // epilogue: lane owns column q; invl lane-local; packed 8B stores
  const float invl = 1.0f / l_run;
  unsigned short* orow = Og + (size_t)(qt * 128 + w * 32 + l31) * HID + h * HD;
#pragma unroll
  for (int db = 0; db < 4; ++db)
#pragma unroll
    for (int rr = 0; rr < 4; ++rr) {
      int d0 = db * 32 + rr * 8 + 4 * hi;
      ushort4 o;
      o.x = f2bf(accO[db][rr * 4 + 0] * invl);
      o.y = f2bf(accO[db][rr * 4 + 1] * invl);
      o.z = f2bf(accO[db][rr * 4 + 2] * invl);
      o.w = f2bf(accO[db][rr * 4 + 3] * invl);
      *(ushort4*)(orow + d0) = o;
    }

  // ---- Wo fp32->bf16 conversion, hidden in causal-load slack ----
  {
    const int gb = blockIdx.y * gridDim.x + blockIdx.x;   // 0..511
    const int total = HID * HID / 4;                      // 4M float4
    for (int i = gb * 256 + tid; i < total; i += 512 * 256) {
      float4 v = ((const float4*)Wo)[i];
      ushort4 o;
      o.x = f2bf(v.x); o.y = f2bf(v.y); o.z = f2bf(v.z); o.w = f2bf(v.w);
      ((ushort4*)woB)[i] = o;
    }
  }
}

// ---------------------------------------------------------------------- launch
extern "C" void kernel_launch(void* const* d_in, const int* in_sizes, int n_in,
                              void* d_out, int out_size, void* d_ws, size_t ws_size,
                              hipStream_t stream) {
  const float* hs   = (const float*)d_in[0];
  const float* cosp = (const float*)d_in[1];
  const float* sinp = (const float*)d_in[2];
  const float* Wq = (const float*)d_in[4];
  const float* Wk = (const float*)d_in[5];
  const float* Wv = (const float*)d_in[6];
  const float* Wo = (const float*)d_in[7];
  float* out = (float*)d_out;

  uint8_t* ws = (uint8_t*)d_ws;
  size_t off = 0;
  auto alloc = [&](size_t bytes) { void* p = ws + off; off += bytes; return p; };
  unsigned short* hidB  = (unsigned short*)alloc((size_t)S_LEN * HID * 2);
  unsigned short* wqkvB = (unsigned short*)alloc((size_t)QKV_STR * HID * 2);
  unsigned short* woB   = (unsigned short*)alloc((size_t)HID * HID * 2);
  unsigned short* qkvB  = (unsigned short*)alloc((size_t)S_LEN * QKV_STR * 2);
  unsigned short* aoB   = (unsigned short*)alloc((size_t)S_LEN * HID * 2);
  unsigned short* vtB   = (unsigned short*)alloc((size_t)NKVH * HD * S_LEN * 2);

  // 1. fp32 -> bf16: hidden + Wq/Wk/Wv (Wo handled inside flash_attn)
  cvt_multi<<<dim3(1024, 4), 256, 0, stream>>>(
      hs, Wq, Wk, Wv,
      hidB, wqkvB, wqkvB + (size_t)HID * HID, wqkvB + (size_t)(HID + 1024) * HID,
      S_LEN * HID / 4, HID * HID / 4, 1024 * HID / 4, 1024 * HID / 4);

  // 2. fused QKV projection with in-epilogue K-RoPE and V-transpose
  gemm_bt<false, true><<<dim3(QKV_STR / 128, S_LEN / 128), 256, 0, stream>>>(
      hidB, wqkvB, qkvB, QKV_STR, HID, cosp, sinp, vtB);

  // 3. flash attention (R9 loop, fused Q-RoPE, anti-paired qt, Wo-cvt epilogue)
  flash_attn<<<dim3(S_LEN / 128, NHEAD), 256, 0, stream>>>(
      qkvB, vtB, cosp, sinp, aoB, Wo, woB);

  // 4. output projection, fp32 straight to d_out (clean R5 codegen)
  gemm_bt<true, false><<<dim3(HID / 128, S_LEN / 128), 256, 0, stream>>>(
      aoB, woB, out, HID, HID, nullptr, nullptr, nullptr);
}